// Round 11
// baseline (12945.291 us; speedup 1.0000x reference)
//
#include <hip/hip_runtime.h>

#define T_LEN 2048

typedef _Float16 f16x8 __attribute__((ext_vector_type(8)));
typedef float f32x4 __attribute__((ext_vector_type(4)));
typedef unsigned int u32;
typedef unsigned short u16;

__device__ __forceinline__ float sigm(float v) { return 1.f / (1.f + __expf(-v)); }

// ---------- Phase 0: pack Wh k-rows [160,192) into frag-layout f16 (per dir) ----
// slot = (dir, blk=(p*16+w), lane); each thread writes one 16B frag line:
// lane l holds B[k=160+8*(l>>4)+j][col=p*256+16w+(l&15)], j=0..7.
__global__ __launch_bounds__(256) void wh_pack(const float* __restrict__ Wfw,
                                               const float* __restrict__ Wbw,
                                               u16* __restrict__ whk5) {
  const int s = blockIdx.x * 256 + threadIdx.x;  // 0..8191
  const int dir = s >> 12, r = s & 4095;
  const int blk = r >> 6, lane = r & 63;
  const int p = blk >> 4, w = blk & 15;
  const int l15 = lane & 15, l4 = lane >> 4;
  const float* W = dir ? Wbw : Wfw;
  const int col = p * 256 + 16 * w + l15;
  union { _Float16 h[8]; uint4 q; } u;
#pragma unroll
  for (int j = 0; j < 8; ++j)
    u.h[j] = (_Float16)W[(size_t)(256 + 160 + 8 * l4 + j) * 1024 + col];
  *(uint4*)(whk5 + ((size_t)dir * 4096 + (size_t)blk * 64 + lane) * 8) = u.q;
}

// ---------- Phase 1: xg = x @ Wx + bias (+1 on forget), f16, layout [d*4+p] ----
__global__ __launch_bounds__(256) void xg_gemm(
    const float* __restrict__ x, const float* __restrict__ Wfw,
    const float* __restrict__ bfw, const float* __restrict__ Wbw,
    const float* __restrict__ bbw, u16* __restrict__ xg, int t0, int chunkT) {
  const int dir = blockIdx.z;
  const int mrow0 = blockIdx.x * 64;
  const int ncol0 = blockIdx.y * 64;
  const float* W = dir ? Wbw : Wfw;
  const float* bias = dir ? bbw : bfw;
  const int tid = threadIdx.x;
  const int w = tid >> 6, lane = tid & 63, l15 = lane & 15, l4 = lane >> 4;

  __shared__ _Float16 At[64 * 32];
  __shared__ _Float16 Bt[64 * 32];

  const int b = mrow0 / chunkT;
  const int sbase = mrow0 % chunkT;

  f32x4 acc[4] = {{0,0,0,0},{0,0,0,0},{0,0,0,0},{0,0,0,0}};
  const int ar = tid >> 2, acq = tid & 3;
  const int bc = tid >> 2, bkq = tid & 3;

  for (int kk0 = 0; kk0 < 256; kk0 += 32) {
    {
      const int sloc = sbase + ar;
      const int tx = dir ? (T_LEN - 1 - (t0 + sloc)) : (t0 + sloc);
      const float* xr = x + ((size_t)b * T_LEN + tx) * 256 + kk0 + 8 * acq;
      f32x4 v0 = *(const f32x4*)xr;
      f32x4 v1 = *(const f32x4*)(xr + 4);
      union { _Float16 h[8]; uint4 q; } u;
#pragma unroll
      for (int j = 0; j < 4; ++j) { u.h[j] = (_Float16)v0[j]; u.h[4 + j] = (_Float16)v1[j]; }
      int byte = ar * 64 + 16 * acq;  byte ^= (ar & 3) << 4;
      *(uint4*)((char*)At + byte) = u.q;
    }
    {
      const float* wc = W + (size_t)(kk0 + 8 * bkq) * 1024 + ncol0 + bc;
      union { _Float16 h[8]; uint4 q; } u;
#pragma unroll
      for (int j = 0; j < 8; ++j) u.h[j] = (_Float16)wc[(size_t)j * 1024];
      int byte = bc * 64 + 16 * bkq;  byte ^= (bc & 3) << 4;
      *(uint4*)((char*)Bt + byte) = u.q;
    }
    __syncthreads();
    f16x8 bfrag;
    {
      const int col = w * 16 + l15;
      int byte = col * 64 + 16 * l4;  byte ^= (col & 3) << 4;
      bfrag = *(const f16x8*)((char*)Bt + byte);
    }
#pragma unroll
    for (int mt = 0; mt < 4; ++mt) {
      const int row = mt * 16 + l15;
      int byte = row * 64 + 16 * l4;  byte ^= (row & 3) << 4;
      f16x8 afrag = *(const f16x8*)((char*)At + byte);
      acc[mt] = __builtin_amdgcn_mfma_f32_16x16x32_f16(afrag, bfrag, acc[mt], 0, 0, 0);
    }
    __syncthreads();
  }
  const int gcol = ncol0 + w * 16 + l15;
  const int pp = gcol >> 8, dd = gcol & 255;
  const float badd = bias[gcol] + ((pp == 2) ? 1.f : 0.f);  // forget = block 2
#pragma unroll
  for (int mt = 0; mt < 4; ++mt) {
#pragma unroll
    for (int v = 0; v < 4; ++v) {
      const int sloc = sbase + mt * 16 + 4 * l4 + v;
      union { _Float16 hf; u16 us; } cv;
      cv.hf = (_Float16)(acc[mt][v] + badd);
      xg[((size_t)(dir * 32 + b) * chunkT + sloc) * 1024 + dd * 4 + pp] = cv.us;
    }
  }
}

// ---------- Phase 2: recurrence, one WG per (dir, batch-half); NO cross-WG sync.
// 4 WGs x 1024 thr (16 waves). Wave w owns dims 16w..16w+15 x all 4 parts
// (cols p*256+16w+l15) -> cell fully in-register, zero shuffles.
// Wh: kt0..4 in VGPR (80), kt5 from L2 frag-pack, kt6..7 from LDS (128KB).
__global__ __launch_bounds__(1024) void rnn_chunk(
    const u16* __restrict__ xg, const float* __restrict__ Wfw,
    const float* __restrict__ Wbw, const u16* __restrict__ whk5,
    float* __restrict__ out, float* __restrict__ state_c,
    u16* __restrict__ state_h, int t0, int t1, int chunkT) {
  const int g = blockIdx.x;
  const int dir = g >> 1, bh = g & 1;
  const int tid = threadIdx.x;
  const int w = tid >> 6, lane = tid & 63, l15 = lane & 15, l4 = lane >> 4;
  const float* W = dir ? Wbw : Wfw;

  __shared__ u16 WL[2 * 4 * 16 * 64 * 8];   // 128KB: [kt2][p][w][lane][8]
  __shared__ _Float16 H[2][16 * 256];       // 16KB dbuf, [seq][256] swizzled

  // wB: kt 0..4 (k 0..159) x 4 parts
  f16x8 wB[5][4];
#pragma unroll
  for (int kt = 0; kt < 5; ++kt)
#pragma unroll
    for (int p = 0; p < 4; ++p) {
      const int col = p * 256 + 16 * w + l15;
      f16x8 h;
#pragma unroll
      for (int j = 0; j < 8; ++j)
        h[j] = (_Float16)W[(size_t)(256 + kt * 32 + l4 * 8 + j) * 1024 + col];
      wB[kt][p] = h;
    }
  // fill WL (kt 6,7 -> k 192..255): each thread writes its own frag lines
#pragma unroll
  for (int kt2 = 0; kt2 < 2; ++kt2)
#pragma unroll
    for (int p = 0; p < 4; ++p) {
      const int col = p * 256 + 16 * w + l15;
      union { _Float16 h[8]; uint4 q; } u;
#pragma unroll
      for (int j = 0; j < 8; ++j)
        u.h[j] = (_Float16)W[(size_t)(256 + 192 + kt2 * 32 + l4 * 8 + j) * 1024 + col];
      *(uint4*)&WL[(((kt2 * 4 + p) * 16 + w) * 64 + lane) * 8] = u.q;
    }

  const int d = 16 * w + l15;  // this thread's h-dim
  float c[4];
  {  // restore/init state; stage h into H[0]
#pragma unroll
    for (int v = 0; v < 4; ++v) {
      const int seq = 4 * l4 + v;
      const int sidx = (dir * 32 + bh * 16 + seq) * 256 + d;
      u16 hb;
      if (t0 == 0) { c[v] = 0.f; hb = 0; }
      else { c[v] = state_c[sidx]; hb = state_h[sidx]; }
      int byte = seq * 512 + d * 2;  byte ^= (seq & 7) << 4;
      *(u16*)((char*)H[0] + byte) = hb;
    }
  }
  __syncthreads();

  const u16* wk5 = whk5 + ((size_t)dir * 4096 + (size_t)w * 64 + lane) * 8;
  const size_t xgrow0 = (size_t)(dir * 32 + bh * 16 + 4 * l4) * chunkT;

  for (int s = t0; s < t1; ++s) {
    const int cur = (s - t0) & 1;
    const _Float16* Hc = H[cur];

    // issue L2 reads early: kt5 frags (4) + xg (4 x 8B)
    f16x8 k5[4];
#pragma unroll
    for (int p = 0; p < 4; ++p)
      k5[p] = *(const f16x8*)(wk5 + (size_t)p * (16 * 64 * 8));
    ushort4 xv[4];
#pragma unroll
    for (int v = 0; v < 4; ++v)
      xv[v] = *(const ushort4*)(xg + ((xgrow0 + (size_t)v * chunkT) + (s - t0)) * 1024 + d * 4);

    f32x4 acc[4] = {{0,0,0,0},{0,0,0,0},{0,0,0,0},{0,0,0,0}};
#pragma unroll
    for (int kt = 0; kt < 5; ++kt) {  // VGPR weights
      int byte = l15 * 512 + (kt * 32 + l4 * 8) * 2;  byte ^= (l15 & 7) << 4;
      f16x8 a = *(const f16x8*)((const char*)Hc + byte);
#pragma unroll
      for (int p = 0; p < 4; ++p)
        acc[p] = __builtin_amdgcn_mfma_f32_16x16x32_f16(a, wB[kt][p], acc[p], 0, 0, 0);
    }
#pragma unroll
    for (int kt2 = 0; kt2 < 2; ++kt2) {  // LDS-streamed weights (k 192..255)
      int byte = l15 * 512 + ((6 + kt2) * 32 + l4 * 8) * 2;  byte ^= (l15 & 7) << 4;
      f16x8 a = *(const f16x8*)((const char*)Hc + byte);
#pragma unroll
      for (int p = 0; p < 4; ++p) {
        f16x8 bb = *(const f16x8*)&WL[(((kt2 * 4 + p) * 16 + w) * 64 + lane) * 8];
        acc[p] = __builtin_amdgcn_mfma_f32_16x16x32_f16(a, bb, acc[p], 0, 0, 0);
      }
    }
    {  // L2-streamed kt5 (k 160..191) — loads have had time to land
      int byte = l15 * 512 + (5 * 32 + l4 * 8) * 2;  byte ^= (l15 & 7) << 4;
      f16x8 a = *(const f16x8*)((const char*)Hc + byte);
#pragma unroll
      for (int p = 0; p < 4; ++p)
        acc[p] = __builtin_amdgcn_mfma_f32_16x16x32_f16(a, k5[p], acc[p], 0, 0, 0);
    }

    // in-register cell: acc[p][v] = gate p of (seq=4*l4+v, dim=d)
    const int tx = dir ? (T_LEN - 1 - s) : s;
#pragma unroll
    for (int v = 0; v < 4; ++v) {
      const int seq = 4 * l4 + v;
      const float gi = acc[0][v] + (float)*(const _Float16*)&xv[v].x;
      const float gj = acc[1][v] + (float)*(const _Float16*)&xv[v].y;
      const float gf = acc[2][v] + (float)*(const _Float16*)&xv[v].z;
      const float go = acc[3][v] + (float)*(const _Float16*)&xv[v].w;
      c[v] = c[v] * sigm(gf) + sigm(gi) * (2.f * sigm(gj + gj) - 1.f);
      const float h = (2.f * sigm(c[v] + c[v]) - 1.f) * sigm(go);
      union { _Float16 hf; u16 us; } cv;
      cv.hf = (_Float16)h;
      int byte = seq * 512 + d * 2;  byte ^= (seq & 7) << 4;
      *(u16*)((char*)H[cur ^ 1] + byte) = cv.us;
      __builtin_nontemporal_store(
          h, out + ((size_t)(bh * 16 + seq) * T_LEN + tx) * 512 + dir * 256 + d);
    }
    __syncthreads();  // H[next] complete before next step's reads
  }
  // save state (read h back from the last-written H buffer)
#pragma unroll
  for (int v = 0; v < 4; ++v) {
    const int seq = 4 * l4 + v;
    const int sidx = (dir * 32 + bh * 16 + seq) * 256 + d;
    state_c[sidx] = c[v];
    int byte = seq * 512 + d * 2;  byte ^= (seq & 7) << 4;
    state_h[sidx] = *(const u16*)((const char*)H[(t1 - t0) & 1] + byte);
  }
}

extern "C" void kernel_launch(void* const* d_in, const int* in_sizes, int n_in,
                              void* d_out, int out_size, void* d_ws,
                              size_t ws_size, hipStream_t stream) {
  const float* x = (const float*)d_in[0];
  const float* Wfw = (const float*)d_in[1];
  const float* bfw = (const float*)d_in[2];
  const float* Wbw = (const float*)d_in[3];
  const float* bbw = (const float*)d_in[4];
  float* out = (float*)d_out;

  // ws: [0,64K) state_c | [64K,96K) state_h | [128K,256K) whk5 | [1M,..) xg
  float* state_c = (float*)d_ws;
  u16* state_h = (u16*)((char*)d_ws + 64 * 1024);
  u16* whk5 = (u16*)((char*)d_ws + 128 * 1024);
  u16* xg = (u16*)((char*)d_ws + (1 << 20));

  int chunkT = 1024;
  while (chunkT > 64 && (size_t)131072 * chunkT + (1 << 20) > ws_size)
    chunkT >>= 1;

  wh_pack<<<dim3(32), dim3(256), 0, stream>>>(Wfw, Wbw, whk5);
  for (int t0 = 0; t0 < T_LEN; t0 += chunkT) {
    xg_gemm<<<dim3((32 * chunkT) / 64, 16, 2), dim3(256), 0, stream>>>(
        x, Wfw, bfw, Wbw, bbw, xg, t0, chunkT);
    rnn_chunk<<<dim3(4), dim3(1024), 0, stream>>>(
        xg, Wfw, Wbw, whk5, out, state_c, state_h, t0, t0 + chunkT, chunkT);
  }
}

// Round 14
// 12495.152 us; speedup vs baseline: 1.0360x; 1.0360x over previous
//
#include <hip/hip_runtime.h>

#define T_LEN 2048

typedef _Float16 f16x8 __attribute__((ext_vector_type(8)));
typedef float f32x4 __attribute__((ext_vector_type(4)));
typedef unsigned int u32;
typedef unsigned short u16;

__device__ __forceinline__ float sigm(float v) { return 1.f / (1.f + __expf(-v)); }

// ======== whk frag layout (SINGLE SOURCE OF TRUTH, both sides) ========
// line L(kt2,p,w,half) = kt2*64 + p*16 + w*2 + half   (bijective, [0,128))
//   bit fields: half=bit0, w=bits1-3, p=bits4-5, kt2=bit6
// u16 address = dir*65536 + L*512 + lane*8
// lane l holds B[k = 192+32*kt2+8*(l>>4)+j][col = p*256+32w+16half+(l&15)].

// ---------- Phase 0: pack Wh k-rows [192,256) into frag-layout f16 ----------
__global__ __launch_bounds__(256) void wh_pack(const float* __restrict__ Wfw,
                                               const float* __restrict__ Wbw,
                                               u16* __restrict__ whk) {
  const int s = blockIdx.x * 256 + threadIdx.x;  // 0..16383
  const int dir = s >> 13, r = s & 8191;
  const int lane = r & 63, q = r >> 6;  // q = line L in [0,128)
  const int half = q & 1, w = (q >> 1) & 7, p = (q >> 4) & 3, kt2 = q >> 6;
  const int l15 = lane & 15, l4 = lane >> 4;
  const float* W = dir ? Wbw : Wfw;
  const int col = p * 256 + 32 * w + 16 * half + l15;
  union { _Float16 h[8]; uint4 qq; } u;
#pragma unroll
  for (int j = 0; j < 8; ++j)
    u.h[j] = (_Float16)W[(size_t)(256 + 192 + kt2 * 32 + 8 * l4 + j) * 1024 + col];
  *(uint4*)(whk + ((size_t)dir * 8192 + r) * 8) = u.qq;  // = dir*65536 + q*512 + lane*8
}

// ---------- Phase 1: xg = x @ Wx + bias (+1 on forget), f16, layout [d*4+p] ----
__global__ __launch_bounds__(256) void xg_gemm(
    const float* __restrict__ x, const float* __restrict__ Wfw,
    const float* __restrict__ bfw, const float* __restrict__ Wbw,
    const float* __restrict__ bbw, u16* __restrict__ xg, int t0, int chunkT) {
  const int dir = blockIdx.z;
  const int mrow0 = blockIdx.x * 64;
  const int ncol0 = blockIdx.y * 64;
  const float* W = dir ? Wbw : Wfw;
  const float* bias = dir ? bbw : bfw;
  const int tid = threadIdx.x;
  const int w = tid >> 6, lane = tid & 63, l15 = lane & 15, l4 = lane >> 4;

  __shared__ _Float16 At[64 * 32];
  __shared__ _Float16 Bt[64 * 32];

  const int b = mrow0 / chunkT;
  const int sbase = mrow0 % chunkT;

  f32x4 acc[4] = {{0,0,0,0},{0,0,0,0},{0,0,0,0},{0,0,0,0}};
  const int ar = tid >> 2, acq = tid & 3;
  const int bc = tid >> 2, bkq = tid & 3;

  for (int kk0 = 0; kk0 < 256; kk0 += 32) {
    {
      const int sloc = sbase + ar;
      const int tx = dir ? (T_LEN - 1 - (t0 + sloc)) : (t0 + sloc);
      const float* xr = x + ((size_t)b * T_LEN + tx) * 256 + kk0 + 8 * acq;
      f32x4 v0 = *(const f32x4*)xr;
      f32x4 v1 = *(const f32x4*)(xr + 4);
      union { _Float16 h[8]; uint4 q; } u;
#pragma unroll
      for (int j = 0; j < 4; ++j) { u.h[j] = (_Float16)v0[j]; u.h[4 + j] = (_Float16)v1[j]; }
      int byte = ar * 64 + 16 * acq;  byte ^= (ar & 3) << 4;
      *(uint4*)((char*)At + byte) = u.q;
    }
    {
      const float* wc = W + (size_t)(kk0 + 8 * bkq) * 1024 + ncol0 + bc;
      union { _Float16 h[8]; uint4 q; } u;
#pragma unroll
      for (int j = 0; j < 8; ++j) u.h[j] = (_Float16)wc[(size_t)j * 1024];
      int byte = bc * 64 + 16 * bkq;  byte ^= (bc & 3) << 4;
      *(uint4*)((char*)Bt + byte) = u.q;
    }
    __syncthreads();
    f16x8 bfrag;
    {
      const int col = w * 16 + l15;
      int byte = col * 64 + 16 * l4;  byte ^= (col & 3) << 4;
      bfrag = *(const f16x8*)((char*)Bt + byte);
    }
#pragma unroll
    for (int mt = 0; mt < 4; ++mt) {
      const int row = mt * 16 + l15;
      int byte = row * 64 + 16 * l4;  byte ^= (row & 3) << 4;
      f16x8 afrag = *(const f16x8*)((char*)At + byte);
      acc[mt] = __builtin_amdgcn_mfma_f32_16x16x32_f16(afrag, bfrag, acc[mt], 0, 0, 0);
    }
    __syncthreads();
  }
  const int gcol = ncol0 + w * 16 + l15;
  const int pp = gcol >> 8, dd = gcol & 255;
  const float badd = bias[gcol] + ((pp == 2) ? 1.f : 0.f);  // forget = block 2
#pragma unroll
  for (int mt = 0; mt < 4; ++mt) {
#pragma unroll
    for (int v = 0; v < 4; ++v) {
      const int sloc = sbase + mt * 16 + 4 * l4 + v;
      union { _Float16 hf; u16 us; } cv;
      cv.hf = (_Float16)(acc[mt][v] + badd);
      xg[((size_t)(dir * 32 + b) * chunkT + sloc) * 1024 + dd * 4 + pp] = cv.us;
    }
  }
}

// ---------- Phase 2: recurrence. 4 WGs x 512 thr (8 waves, 256 VGPR/wave).
// Wave w owns dims [32w..32w+32) x all 4 parts (8 col-tiles, acc[4][2]).
// Wh K=256 split: kt0..3 VGPR (128), kt4..5 LDS (128KB), kt6..7 L2-streamed.
__global__ __launch_bounds__(512, 2) void rnn_chunk(
    const u16* __restrict__ xg, const float* __restrict__ Wfw,
    const float* __restrict__ Wbw, const u16* __restrict__ whk,
    float* __restrict__ out, float* __restrict__ state_c,
    u16* __restrict__ state_h, int t0, int t1, int chunkT) {
  const int g = blockIdx.x;
  const int dir = g >> 1, bh = g & 1;
  const int tid = threadIdx.x;
  const int w = tid >> 6, lane = tid & 63, l15 = lane & 15, l4 = lane >> 4;
  const float* W = dir ? Wbw : Wfw;

  __shared__ u16 WL[2][4][8][2][512];   // 128KB: [kt2][p][w][half][lane*8]
  __shared__ _Float16 H[2][16 * 256];   // 16KB dbuf, [seq][256] swizzled

  // ---- kt0..3 -> registers: 32 frags = 128 VGPR ----
  f16x8 wB[4][4][2];
#pragma unroll
  for (int kt = 0; kt < 4; ++kt)
#pragma unroll
    for (int p = 0; p < 4; ++p)
#pragma unroll
      for (int hf = 0; hf < 2; ++hf) {
        const int col = p * 256 + 32 * w + 16 * hf + l15;
        f16x8 h;
#pragma unroll
        for (int j = 0; j < 8; ++j)
          h[j] = (_Float16)W[(size_t)(256 + kt * 32 + l4 * 8 + j) * 1024 + col];
        wB[kt][p][hf] = h;
      }
  // ---- kt4..5 -> LDS ----
#pragma unroll
  for (int kt2 = 0; kt2 < 2; ++kt2)
#pragma unroll
    for (int p = 0; p < 4; ++p)
#pragma unroll
      for (int hf = 0; hf < 2; ++hf) {
        const int col = p * 256 + 32 * w + 16 * hf + l15;
        union { _Float16 h[8]; uint4 q; } u;
#pragma unroll
        for (int j = 0; j < 8; ++j)
          u.h[j] = (_Float16)W[(size_t)(256 + 128 + kt2 * 32 + l4 * 8 + j) * 1024 + col];
        *(uint4*)&WL[kt2][p][w][hf][lane * 8] = u.q;
      }

  const int d0 = 32 * w + l15, d1 = d0 + 16;
  float c0[4], c1[4];
  {  // restore/init state; stage h into H[0]
#pragma unroll
    for (int v = 0; v < 4; ++v) {
      const int seq = 4 * l4 + v;
      const int si0 = (dir * 32 + bh * 16 + seq) * 256 + d0;
      const int si1 = si0 + 16;
      u16 hb0, hb1;
      if (t0 == 0) { c0[v] = 0.f; c1[v] = 0.f; hb0 = 0; hb1 = 0; }
      else { c0[v] = state_c[si0]; c1[v] = state_c[si1];
             hb0 = state_h[si0]; hb1 = state_h[si1]; }
      int byte = seq * 512 + d0 * 2;  byte ^= (seq & 7) << 4;
      *(u16*)((char*)H[0] + byte) = hb0;
      byte = seq * 512 + d1 * 2;  byte ^= (seq & 7) << 4;
      *(u16*)((char*)H[0] + byte) = hb1;
    }
  }
  __syncthreads();

  // consumer base per the layout formula: dir*65536 + w*1024 + lane*8;
  // + kt2*32768 + p*8192 + half*512   (L = kt2*64 + p*16 + w*2 + half)
  const u16* wkb = whk + (size_t)dir * 65536 + (size_t)w * 1024 + lane * 8;
  const size_t xgrow0 = (size_t)(dir * 32 + bh * 16 + 4 * l4) * chunkT;

#define AFRAG(kt)                                                        \
  ({ int byte_ = l15 * 512 + ((kt) * 32 + l4 * 8) * 2;                   \
     byte_ ^= (l15 & 7) << 4;                                            \
     *(const f16x8*)((const char*)Hc + byte_); })

  for (int s = t0; s < t1; ++s) {
    const int cur = (s - t0) & 1;
    const _Float16* Hc = H[cur];
    const int sloc = s - t0;

    // early L2 issues: batch A (kt6: p0-1) + xg
    f16x8 kA[4];
#pragma unroll
    for (int i = 0; i < 4; ++i)  // i = p*2+half, p in {0,1}
      kA[i] = *(const f16x8*)(wkb + (i >> 1) * 8192 + (i & 1) * 512);
    ushort4 xa[4], xb[4];
#pragma unroll
    for (int v = 0; v < 4; ++v) {
      const u16* xp = xg + ((xgrow0 + (size_t)v * chunkT) + sloc) * 1024;
      xa[v] = *(const ushort4*)(xp + d0 * 4);
      xb[v] = *(const ushort4*)(xp + d1 * 4);
    }

    f32x4 acc[4][2] = {};
    // kt0..3 (VGPR weights)
#pragma unroll
    for (int kt = 0; kt < 4; ++kt) {
      f16x8 a = AFRAG(kt);
#pragma unroll
      for (int p = 0; p < 4; ++p)
#pragma unroll
        for (int hf = 0; hf < 2; ++hf)
          acc[p][hf] = __builtin_amdgcn_mfma_f32_16x16x32_f16(a, wB[kt][p][hf], acc[p][hf], 0, 0, 0);
    }
    // batch B issue (kt6: p2-3)
    f16x8 kB[4];
#pragma unroll
    for (int i = 0; i < 4; ++i)
      kB[i] = *(const f16x8*)(wkb + (2 + (i >> 1)) * 8192 + (i & 1) * 512);
    // kt4..5 (LDS weights)
#pragma unroll
    for (int kt2 = 0; kt2 < 2; ++kt2) {
      f16x8 a = AFRAG(4 + kt2);
#pragma unroll
      for (int p = 0; p < 4; ++p)
#pragma unroll
        for (int hf = 0; hf < 2; ++hf) {
          f16x8 bb = *(const f16x8*)&WL[kt2][p][w][hf][lane * 8];
          acc[p][hf] = __builtin_amdgcn_mfma_f32_16x16x32_f16(a, bb, acc[p][hf], 0, 0, 0);
        }
    }
    // batch C issue (kt7: p0-1), then kt6/kt7 MFMAs
    f16x8 kC[4];
#pragma unroll
    for (int i = 0; i < 4; ++i)
      kC[i] = *(const f16x8*)(wkb + 32768 + (i >> 1) * 8192 + (i & 1) * 512);
    {
      f16x8 a = AFRAG(6);
#pragma unroll
      for (int i = 0; i < 4; ++i)
        acc[i >> 1][i & 1] = __builtin_amdgcn_mfma_f32_16x16x32_f16(a, kA[i], acc[i >> 1][i & 1], 0, 0, 0);
      f16x8 kD[4];
#pragma unroll
      for (int i = 0; i < 4; ++i)
        kD[i] = *(const f16x8*)(wkb + 32768 + (2 + (i >> 1)) * 8192 + (i & 1) * 512);
#pragma unroll
      for (int i = 0; i < 4; ++i)
        acc[2 + (i >> 1)][i & 1] = __builtin_amdgcn_mfma_f32_16x16x32_f16(a, kB[i], acc[2 + (i >> 1)][i & 1], 0, 0, 0);
      f16x8 a7 = AFRAG(7);
#pragma unroll
      for (int i = 0; i < 4; ++i)
        acc[i >> 1][i & 1] = __builtin_amdgcn_mfma_f32_16x16x32_f16(a7, kC[i], acc[i >> 1][i & 1], 0, 0, 0);
#pragma unroll
      for (int i = 0; i < 4; ++i)
        acc[2 + (i >> 1)][i & 1] = __builtin_amdgcn_mfma_f32_16x16x32_f16(a7, kD[i], acc[2 + (i >> 1)][i & 1], 0, 0, 0);
    }

    // ---- in-register cell: acc[p][half][v] = gate p of (seq=4*l4+v, dim) ----
    const int tx = dir ? (T_LEN - 1 - s) : s;
#pragma unroll
    for (int v = 0; v < 4; ++v) {
      const int seq = 4 * l4 + v;
      const float gi0 = acc[0][0][v] + (float)*(const _Float16*)&xa[v].x;
      const float gj0 = acc[1][0][v] + (float)*(const _Float16*)&xa[v].y;
      const float gf0 = acc[2][0][v] + (float)*(const _Float16*)&xa[v].z;
      const float go0 = acc[3][0][v] + (float)*(const _Float16*)&xa[v].w;
      const float gi1 = acc[0][1][v] + (float)*(const _Float16*)&xb[v].x;
      const float gj1 = acc[1][1][v] + (float)*(const _Float16*)&xb[v].y;
      const float gf1 = acc[2][1][v] + (float)*(const _Float16*)&xb[v].z;
      const float go1 = acc[3][1][v] + (float)*(const _Float16*)&xb[v].w;
      c0[v] = c0[v] * sigm(gf0) + sigm(gi0) * (2.f * sigm(gj0 + gj0) - 1.f);
      c1[v] = c1[v] * sigm(gf1) + sigm(gi1) * (2.f * sigm(gj1 + gj1) - 1.f);
      const float h0 = (2.f * sigm(c0[v] + c0[v]) - 1.f) * sigm(go0);
      const float h1 = (2.f * sigm(c1[v] + c1[v]) - 1.f) * sigm(go1);
      union { _Float16 hf; u16 us; } v0, v1;
      v0.hf = (_Float16)h0;
      v1.hf = (_Float16)h1;
      int byte = seq * 512 + d0 * 2;  byte ^= (seq & 7) << 4;
      *(u16*)((char*)H[cur ^ 1] + byte) = v0.us;
      byte = seq * 512 + d1 * 2;  byte ^= (seq & 7) << 4;
      *(u16*)((char*)H[cur ^ 1] + byte) = v1.us;
      float* op = out + ((size_t)(bh * 16 + seq) * T_LEN + tx) * 512 + dir * 256;
      __builtin_nontemporal_store(h0, op + d0);
      __builtin_nontemporal_store(h1, op + d1);
    }
    __syncthreads();  // H[next] complete before next step's reads
  }
#undef AFRAG

  // save state
#pragma unroll
  for (int v = 0; v < 4; ++v) {
    const int seq = 4 * l4 + v;
    const int si0 = (dir * 32 + bh * 16 + seq) * 256 + d0;
    state_c[si0] = c0[v];
    state_c[si0 + 16] = c1[v];
    int byte = seq * 512 + d0 * 2;  byte ^= (seq & 7) << 4;
    state_h[si0] = *(const u16*)((const char*)H[(t1 - t0) & 1] + byte);
    byte = seq * 512 + d1 * 2;  byte ^= (seq & 7) << 4;
    state_h[si0 + 16] = *(const u16*)((const char*)H[(t1 - t0) & 1] + byte);
  }
}

extern "C" void kernel_launch(void* const* d_in, const int* in_sizes, int n_in,
                              void* d_out, int out_size, void* d_ws,
                              size_t ws_size, hipStream_t stream) {
  const float* x = (const float*)d_in[0];
  const float* Wfw = (const float*)d_in[1];
  const float* bfw = (const float*)d_in[2];
  const float* Wbw = (const float*)d_in[3];
  const float* bbw = (const float*)d_in[4];
  float* out = (float*)d_out;

  // ws: [0,64K) state_c | [64K,96K) state_h | [128K,384K) whk | [1M,..) xg
  float* state_c = (float*)d_ws;
  u16* state_h = (u16*)((char*)d_ws + 64 * 1024);
  u16* whk = (u16*)((char*)d_ws + 128 * 1024);
  u16* xg = (u16*)((char*)d_ws + (1 << 20));

  int chunkT = 1024;
  while (chunkT > 64 && (size_t)131072 * chunkT + (1 << 20) > ws_size)
    chunkT >>= 1;

  wh_pack<<<dim3(64), dim3(256), 0, stream>>>(Wfw, Wbw, whk);
  for (int t0 = 0; t0 < T_LEN; t0 += chunkT) {
    xg_gemm<<<dim3((32 * chunkT) / 64, 16, 2), dim3(256), 0, stream>>>(
        x, Wfw, bfw, Wbw, bbw, xg, t0, chunkT);
    rnn_chunk<<<dim3(4), dim3(512), 0, stream>>>(
        xg, Wfw, Wbw, whk, out, state_c, state_h, t0, t0 + chunkT, chunkT);
  }
}

// Round 15
// 12325.426 us; speedup vs baseline: 1.0503x; 1.0138x over previous
//
#include <hip/hip_runtime.h>

#define T_LEN 2048

typedef _Float16 f16x8 __attribute__((ext_vector_type(8)));
typedef float f32x4 __attribute__((ext_vector_type(4)));
typedef unsigned int u32;
typedef unsigned short u16;

__device__ __forceinline__ float sigm(float v) { return 1.f / (1.f + __expf(-v)); }

// ======== whk frag layout (single source of truth) ========
// line L(kt2,p,w,half) = kt2*64 + p*16 + w*2 + half ; u16 addr = dir*65536 + L*512 + lane*8
// lane l holds B[k=192+32*kt2+8*(l>>4)+j][col=p*256+32w+16half+(l&15)]
__global__ __launch_bounds__(256) void wh_pack(const float* __restrict__ Wfw,
                                               const float* __restrict__ Wbw,
                                               u16* __restrict__ whk) {
  const int s = blockIdx.x * 256 + threadIdx.x;
  const int dir = s >> 13, r = s & 8191;
  const int lane = r & 63, q = r >> 6;
  const int half = q & 1, w = (q >> 1) & 7, p = (q >> 4) & 3, kt2 = q >> 6;
  const int l15 = lane & 15, l4 = lane >> 4;
  const float* W = dir ? Wbw : Wfw;
  const int col = p * 256 + 32 * w + 16 * half + l15;
  union { _Float16 h[8]; uint4 qq; } u;
#pragma unroll
  for (int j = 0; j < 8; ++j)
    u.h[j] = (_Float16)W[(size_t)(256 + 192 + kt2 * 32 + 8 * l4 + j) * 1024 + col];
  *(uint4*)(whk + ((size_t)dir * 8192 + r) * 8) = u.qq;
}

// ---------- Phase 1: xg = x @ Wx + bias (+1 forget), f16, layout [d*4+p] ----
__global__ __launch_bounds__(256) void xg_gemm(
    const float* __restrict__ x, const float* __restrict__ Wfw,
    const float* __restrict__ bfw, const float* __restrict__ Wbw,
    const float* __restrict__ bbw, u16* __restrict__ xg, int t0, int chunkT) {
  const int dir = blockIdx.z;
  const int mrow0 = blockIdx.x * 64;
  const int ncol0 = blockIdx.y * 64;
  const float* W = dir ? Wbw : Wfw;
  const float* bias = dir ? bbw : bfw;
  const int tid = threadIdx.x;
  const int w = tid >> 6, lane = tid & 63, l15 = lane & 15, l4 = lane >> 4;

  __shared__ _Float16 At[64 * 32];
  __shared__ _Float16 Bt[64 * 32];

  const int b = mrow0 / chunkT;
  const int sbase = mrow0 % chunkT;

  f32x4 acc0 = {0,0,0,0}, acc1 = {0,0,0,0}, acc2 = {0,0,0,0}, acc3 = {0,0,0,0};
  const int ar = tid >> 2, acq = tid & 3;
  const int bc = tid >> 2, bkq = tid & 3;

  for (int kk0 = 0; kk0 < 256; kk0 += 32) {
    {
      const int sloc = sbase + ar;
      const int tx = dir ? (T_LEN - 1 - (t0 + sloc)) : (t0 + sloc);
      const float* xr = x + ((size_t)b * T_LEN + tx) * 256 + kk0 + 8 * acq;
      f32x4 v0 = *(const f32x4*)xr;
      f32x4 v1 = *(const f32x4*)(xr + 4);
      union { _Float16 h[8]; uint4 q; } u;
#pragma unroll
      for (int j = 0; j < 4; ++j) { u.h[j] = (_Float16)v0[j]; u.h[4 + j] = (_Float16)v1[j]; }
      int byte = ar * 64 + 16 * acq;  byte ^= (ar & 3) << 4;
      *(uint4*)((char*)At + byte) = u.q;
    }
    {
      const float* wc = W + (size_t)(kk0 + 8 * bkq) * 1024 + ncol0 + bc;
      union { _Float16 h[8]; uint4 q; } u;
#pragma unroll
      for (int j = 0; j < 8; ++j) u.h[j] = (_Float16)wc[(size_t)j * 1024];
      int byte = bc * 64 + 16 * bkq;  byte ^= (bc & 3) << 4;
      *(uint4*)((char*)Bt + byte) = u.q;
    }
    __syncthreads();
    f16x8 bfrag;
    {
      const int col = w * 16 + l15;
      int byte = col * 64 + 16 * l4;  byte ^= (col & 3) << 4;
      bfrag = *(const f16x8*)((char*)Bt + byte);
    }
#define XG_MT(mt, accv)                                                   \
    { const int row = mt * 16 + l15;                                      \
      int byte = row * 64 + 16 * l4;  byte ^= (row & 3) << 4;             \
      f16x8 afrag = *(const f16x8*)((char*)At + byte);                    \
      accv = __builtin_amdgcn_mfma_f32_16x16x32_f16(afrag, bfrag, accv, 0, 0, 0); }
    XG_MT(0, acc0) XG_MT(1, acc1) XG_MT(2, acc2) XG_MT(3, acc3)
#undef XG_MT
    __syncthreads();
  }
  const int gcol = ncol0 + w * 16 + l15;
  const int pp = gcol >> 8, dd = gcol & 255;
  const float badd = bias[gcol] + ((pp == 2) ? 1.f : 0.f);
#define XG_ST(mt, accv)                                                   \
  _Pragma("unroll") for (int v = 0; v < 4; ++v) {                         \
    const int sloc = sbase + mt * 16 + 4 * l4 + v;                        \
    union { _Float16 hf; u16 us; } cv;                                    \
    cv.hf = (_Float16)(accv[v] + badd);                                   \
    xg[((size_t)(dir * 32 + b) * chunkT + sloc) * 1024 + dd * 4 + pp] = cv.us; }
  XG_ST(0, acc0) XG_ST(1, acc1) XG_ST(2, acc2) XG_ST(3, acc3)
#undef XG_ST
}

// ---------- Phase 2: recurrence, 4 WGs x 512 thr. ALL-NAMED registers. ----
// Wave w: dims [32w..32w+32) x 4 parts. Wh: kt0..3 named VGPR frags (128),
// kt4..5 LDS (128KB), kt6..7 L2 ping-pong (<=32 live). Cell in-register.
__global__ __launch_bounds__(512, 2) void rnn_chunk(
    const u16* __restrict__ xg, const float* __restrict__ Wfw,
    const float* __restrict__ Wbw, const u16* __restrict__ whk,
    float* __restrict__ out, float* __restrict__ state_c,
    u16* __restrict__ state_h, int t0, int t1, int chunkT) {
  const int g = blockIdx.x;
  const int dir = g >> 1, bh = g & 1;
  const int tid = threadIdx.x;
  const int w = tid >> 6, lane = tid & 63, l15 = lane & 15, l4 = lane >> 4;
  const float* W = dir ? Wbw : Wfw;

  __shared__ u16 WL[2][4][8][2][512];   // 128KB k=128..191
  __shared__ _Float16 H[2][16 * 256];   // 16KB dbuf

  // ---- 32 NAMED weight fragments (kt0..3), literal indices everywhere ----
#define DECL_WB(kt) f16x8 wB##kt##00, wB##kt##01, wB##kt##10, wB##kt##11, \
                          wB##kt##20, wB##kt##21, wB##kt##30, wB##kt##31;
  DECL_WB(0) DECL_WB(1) DECL_WB(2) DECL_WB(3)
#undef DECL_WB
#define LOAD_WB1(kt, p, hf)                                               \
  { const int col = (p) * 256 + 32 * w + 16 * (hf) + l15;                 \
    f16x8 hh;                                                             \
    _Pragma("unroll") for (int j = 0; j < 8; ++j)                         \
      hh[j] = (_Float16)W[(size_t)(256 + (kt) * 32 + l4 * 8 + j) * 1024 + col]; \
    wB##kt##p##hf = hh; }
#define LOAD_WB(kt) LOAD_WB1(kt,0,0) LOAD_WB1(kt,0,1) LOAD_WB1(kt,1,0) LOAD_WB1(kt,1,1) \
                    LOAD_WB1(kt,2,0) LOAD_WB1(kt,2,1) LOAD_WB1(kt,3,0) LOAD_WB1(kt,3,1)
  LOAD_WB(0) LOAD_WB(1) LOAD_WB(2) LOAD_WB(3)
#undef LOAD_WB
#undef LOAD_WB1

  // ---- kt4..5 -> LDS ----
#pragma unroll
  for (int kt2 = 0; kt2 < 2; ++kt2)
#pragma unroll
    for (int p = 0; p < 4; ++p)
#pragma unroll
      for (int hf = 0; hf < 2; ++hf) {
        const int col = p * 256 + 32 * w + 16 * hf + l15;
        union { _Float16 h[8]; uint4 q; } u;
#pragma unroll
        for (int j = 0; j < 8; ++j)
          u.h[j] = (_Float16)W[(size_t)(256 + 128 + kt2 * 32 + l4 * 8 + j) * 1024 + col];
        *(uint4*)&WL[kt2][p][w][hf][lane * 8] = u.q;
      }

  const int d0 = 32 * w + l15, d1 = d0 + 16;
  // H byte offsets (precomputed, named)
  const int seq0 = 4 * l4;
#define HB(seqv, d) ((((seqv) * 512 + (d) * 2)) ^ (((seqv) & 7) << 4))
  const int hb0_0 = HB(seq0, d0), hb0_1 = HB(seq0 + 1, d0), hb0_2 = HB(seq0 + 2, d0), hb0_3 = HB(seq0 + 3, d0);
  const int hb1_0 = HB(seq0, d1), hb1_1 = HB(seq0 + 1, d1), hb1_2 = HB(seq0 + 2, d1), hb1_3 = HB(seq0 + 3, d1);
#undef HB

  float c0_0, c0_1, c0_2, c0_3, c1_0, c1_1, c1_2, c1_3;
  {  // restore/init; stage h into H[0]
#define INITV(v)                                                           \
    { const int sidx = (dir * 32 + bh * 16 + seq0 + v) * 256 + d0;         \
      u16 hq0, hq1;                                                        \
      if (t0 == 0) { c0_##v = 0.f; c1_##v = 0.f; hq0 = 0; hq1 = 0; }       \
      else { c0_##v = state_c[sidx]; c1_##v = state_c[sidx + 16];          \
             hq0 = state_h[sidx]; hq1 = state_h[sidx + 16]; }              \
      *(u16*)((char*)H[0] + hb0_##v) = hq0;                                \
      *(u16*)((char*)H[0] + hb1_##v) = hq1; }
    INITV(0) INITV(1) INITV(2) INITV(3)
#undef INITV
  }
  __syncthreads();

  const u16* wkb = whk + (size_t)dir * 65536 + (size_t)w * 1024 + lane * 8;
  // pointer-increment addressing (named)
  const int tx0 = dir ? (T_LEN - 1 - t0) : t0;
  const long outstep = dir ? -512 : 512;
  float* outp0 = out + ((size_t)(bh * 16 + seq0) * T_LEN + tx0) * 512 + dir * 256;
  float* outp1 = out + ((size_t)(bh * 16 + seq0 + 1) * T_LEN + tx0) * 512 + dir * 256;
  float* outp2 = out + ((size_t)(bh * 16 + seq0 + 2) * T_LEN + tx0) * 512 + dir * 256;
  float* outp3 = out + ((size_t)(bh * 16 + seq0 + 3) * T_LEN + tx0) * 512 + dir * 256;
  const u16* xgp0 = xg + (size_t)((dir * 32 + bh * 16 + seq0) * chunkT) * 1024 + d0 * 4;
  const u16* xgp1 = xg + (size_t)((dir * 32 + bh * 16 + seq0 + 1) * chunkT) * 1024 + d0 * 4;
  const u16* xgp2 = xg + (size_t)((dir * 32 + bh * 16 + seq0 + 2) * chunkT) * 1024 + d0 * 4;
  const u16* xgp3 = xg + (size_t)((dir * 32 + bh * 16 + seq0 + 3) * chunkT) * 1024 + d0 * 4;

#define AFRAG(kt)                                                         \
  ({ int byte_ = l15 * 512 + (kt) * 64 + l4 * 16;                         \
     byte_ ^= (l15 & 7) << 4;                                             \
     *(const f16x8*)((const char*)Hc + byte_); })
#define MFMA8(kt, A)                                                      \
  a00 = __builtin_amdgcn_mfma_f32_16x16x32_f16(A, wB##kt##00, a00, 0, 0, 0); \
  a01 = __builtin_amdgcn_mfma_f32_16x16x32_f16(A, wB##kt##01, a01, 0, 0, 0); \
  a10 = __builtin_amdgcn_mfma_f32_16x16x32_f16(A, wB##kt##10, a10, 0, 0, 0); \
  a11 = __builtin_amdgcn_mfma_f32_16x16x32_f16(A, wB##kt##11, a11, 0, 0, 0); \
  a20 = __builtin_amdgcn_mfma_f32_16x16x32_f16(A, wB##kt##20, a20, 0, 0, 0); \
  a21 = __builtin_amdgcn_mfma_f32_16x16x32_f16(A, wB##kt##21, a21, 0, 0, 0); \
  a30 = __builtin_amdgcn_mfma_f32_16x16x32_f16(A, wB##kt##30, a30, 0, 0, 0); \
  a31 = __builtin_amdgcn_mfma_f32_16x16x32_f16(A, wB##kt##31, a31, 0, 0, 0);
#define MFMA8_LDS(kt2, A)                                                 \
  a00 = __builtin_amdgcn_mfma_f32_16x16x32_f16(A, *(const f16x8*)&WL[kt2][0][w][0][lane * 8], a00, 0, 0, 0); \
  a01 = __builtin_amdgcn_mfma_f32_16x16x32_f16(A, *(const f16x8*)&WL[kt2][0][w][1][lane * 8], a01, 0, 0, 0); \
  a10 = __builtin_amdgcn_mfma_f32_16x16x32_f16(A, *(const f16x8*)&WL[kt2][1][w][0][lane * 8], a10, 0, 0, 0); \
  a11 = __builtin_amdgcn_mfma_f32_16x16x32_f16(A, *(const f16x8*)&WL[kt2][1][w][1][lane * 8], a11, 0, 0, 0); \
  a20 = __builtin_amdgcn_mfma_f32_16x16x32_f16(A, *(const f16x8*)&WL[kt2][2][w][0][lane * 8], a20, 0, 0, 0); \
  a21 = __builtin_amdgcn_mfma_f32_16x16x32_f16(A, *(const f16x8*)&WL[kt2][2][w][1][lane * 8], a21, 0, 0, 0); \
  a30 = __builtin_amdgcn_mfma_f32_16x16x32_f16(A, *(const f16x8*)&WL[kt2][3][w][0][lane * 8], a30, 0, 0, 0); \
  a31 = __builtin_amdgcn_mfma_f32_16x16x32_f16(A, *(const f16x8*)&WL[kt2][3][w][1][lane * 8], a31, 0, 0, 0);

  for (int s = t0; s < t1; ++s) {
    const int cur = (s - t0) & 1;
    const _Float16* Hc = H[cur];
    char* Hn = (char*)H[cur ^ 1];

    // stream batch S0 (kt6: p0,p1) + xg loads (issued early)
    f16x8 sA0 = *(const f16x8*)(wkb + 0);
    f16x8 sA1 = *(const f16x8*)(wkb + 512);
    f16x8 sA2 = *(const f16x8*)(wkb + 8192);
    f16x8 sA3 = *(const f16x8*)(wkb + 8192 + 512);
    ushort4 xa0 = *(const ushort4*)xgp0, xb0 = *(const ushort4*)(xgp0 + 64);
    ushort4 xa1 = *(const ushort4*)xgp1, xb1 = *(const ushort4*)(xgp1 + 64);
    ushort4 xa2 = *(const ushort4*)xgp2, xb2 = *(const ushort4*)(xgp2 + 64);
    ushort4 xa3 = *(const ushort4*)xgp3, xb3 = *(const ushort4*)(xgp3 + 64);

    f32x4 a00 = {0,0,0,0}, a01 = {0,0,0,0}, a10 = {0,0,0,0}, a11 = {0,0,0,0};
    f32x4 a20 = {0,0,0,0}, a21 = {0,0,0,0}, a30 = {0,0,0,0}, a31 = {0,0,0,0};

    { f16x8 A = AFRAG(0); MFMA8(0, A) }
    // stream batch S1 (kt6: p2,p3)
    f16x8 sB0 = *(const f16x8*)(wkb + 2 * 8192);
    f16x8 sB1 = *(const f16x8*)(wkb + 2 * 8192 + 512);
    f16x8 sB2 = *(const f16x8*)(wkb + 3 * 8192);
    f16x8 sB3 = *(const f16x8*)(wkb + 3 * 8192 + 512);
    { f16x8 A = AFRAG(1); MFMA8(1, A) }
    { f16x8 A = AFRAG(2); MFMA8(2, A) }
    { f16x8 A = AFRAG(3); MFMA8(3, A) }
    { f16x8 A = AFRAG(4); MFMA8_LDS(0, A) }
    // use S0 (kt6 p0,p1), then reload sA with kt7 p0,p1
    {
      f16x8 A = AFRAG(6);
      a00 = __builtin_amdgcn_mfma_f32_16x16x32_f16(A, sA0, a00, 0, 0, 0);
      a01 = __builtin_amdgcn_mfma_f32_16x16x32_f16(A, sA1, a01, 0, 0, 0);
      a10 = __builtin_amdgcn_mfma_f32_16x16x32_f16(A, sA2, a10, 0, 0, 0);
      a11 = __builtin_amdgcn_mfma_f32_16x16x32_f16(A, sA3, a11, 0, 0, 0);
      sA0 = *(const f16x8*)(wkb + 32768);
      sA1 = *(const f16x8*)(wkb + 32768 + 512);
      sA2 = *(const f16x8*)(wkb + 32768 + 8192);
      sA3 = *(const f16x8*)(wkb + 32768 + 8192 + 512);
      { f16x8 A5 = AFRAG(5); MFMA8_LDS(1, A5) }
      // use S1 (kt6 p2,p3), reload sB with kt7 p2,p3
      a20 = __builtin_amdgcn_mfma_f32_16x16x32_f16(A, sB0, a20, 0, 0, 0);
      a21 = __builtin_amdgcn_mfma_f32_16x16x32_f16(A, sB1, a21, 0, 0, 0);
      a30 = __builtin_amdgcn_mfma_f32_16x16x32_f16(A, sB2, a30, 0, 0, 0);
      a31 = __builtin_amdgcn_mfma_f32_16x16x32_f16(A, sB3, a31, 0, 0, 0);
      sB0 = *(const f16x8*)(wkb + 32768 + 2 * 8192);
      sB1 = *(const f16x8*)(wkb + 32768 + 2 * 8192 + 512);
      sB2 = *(const f16x8*)(wkb + 32768 + 3 * 8192);
      sB3 = *(const f16x8*)(wkb + 32768 + 3 * 8192 + 512);
      f16x8 A7 = AFRAG(7);
      a00 = __builtin_amdgcn_mfma_f32_16x16x32_f16(A7, sA0, a00, 0, 0, 0);
      a01 = __builtin_amdgcn_mfma_f32_16x16x32_f16(A7, sA1, a01, 0, 0, 0);
      a10 = __builtin_amdgcn_mfma_f32_16x16x32_f16(A7, sA2, a10, 0, 0, 0);
      a11 = __builtin_amdgcn_mfma_f32_16x16x32_f16(A7, sA3, a11, 0, 0, 0);
      a20 = __builtin_amdgcn_mfma_f32_16x16x32_f16(A7, sB0, a20, 0, 0, 0);
      a21 = __builtin_amdgcn_mfma_f32_16x16x32_f16(A7, sB1, a21, 0, 0, 0);
      a30 = __builtin_amdgcn_mfma_f32_16x16x32_f16(A7, sB2, a30, 0, 0, 0);
      a31 = __builtin_amdgcn_mfma_f32_16x16x32_f16(A7, sB3, a31, 0, 0, 0);
    }

    // ---- cell (named, fully literal) ----
#define CELL(v)                                                           \
    { float gi0 = a00[v] + (float)*(const _Float16*)&xa##v.x;             \
      float gj0 = a10[v] + (float)*(const _Float16*)&xa##v.y;             \
      float gf0 = a20[v] + (float)*(const _Float16*)&xa##v.z;             \
      float go0 = a30[v] + (float)*(const _Float16*)&xa##v.w;             \
      float gi1 = a01[v] + (float)*(const _Float16*)&xb##v.x;             \
      float gj1 = a11[v] + (float)*(const _Float16*)&xb##v.y;             \
      float gf1 = a21[v] + (float)*(const _Float16*)&xb##v.z;             \
      float go1 = a31[v] + (float)*(const _Float16*)&xb##v.w;             \
      c0_##v = c0_##v * sigm(gf0) + sigm(gi0) * (2.f * sigm(gj0 + gj0) - 1.f); \
      c1_##v = c1_##v * sigm(gf1) + sigm(gi1) * (2.f * sigm(gj1 + gj1) - 1.f); \
      float h0 = (2.f * sigm(c0_##v + c0_##v) - 1.f) * sigm(go0);         \
      float h1 = (2.f * sigm(c1_##v + c1_##v) - 1.f) * sigm(go1);         \
      union { _Float16 hf; u16 us; } q0, q1;                              \
      q0.hf = (_Float16)h0; q1.hf = (_Float16)h1;                         \
      *(u16*)(Hn + hb0_##v) = q0.us;                                      \
      *(u16*)(Hn + hb1_##v) = q1.us;                                      \
      __builtin_nontemporal_store(h0, outp##v + d0);                      \
      __builtin_nontemporal_store(h1, outp##v + d1); }
    CELL(0) CELL(1) CELL(2) CELL(3)
#undef CELL

    xgp0 += 1024; xgp1 += 1024; xgp2 += 1024; xgp3 += 1024;
    outp0 += outstep; outp1 += outstep; outp2 += outstep; outp3 += outstep;
    __syncthreads();
  }
#undef AFRAG
#undef MFMA8
#undef MFMA8_LDS

  // save state
  {
    char* Hl = (char*)H[(t1 - t0) & 1];
#define SAVEV(v)                                                          \
    { const int sidx = (dir * 32 + bh * 16 + seq0 + v) * 256 + d0;        \
      state_c[sidx] = c0_##v; state_c[sidx + 16] = c1_##v;                \
      state_h[sidx] = *(const u16*)(Hl + hb0_##v);                        \
      state_h[sidx + 16] = *(const u16*)(Hl + hb1_##v); }
    SAVEV(0) SAVEV(1) SAVEV(2) SAVEV(3)
#undef SAVEV
  }
}

extern "C" void kernel_launch(void* const* d_in, const int* in_sizes, int n_in,
                              void* d_out, int out_size, void* d_ws,
                              size_t ws_size, hipStream_t stream) {
  const float* x = (const float*)d_in[0];
  const float* Wfw = (const float*)d_in[1];
  const float* bfw = (const float*)d_in[2];
  const float* Wbw = (const float*)d_in[3];
  const float* bbw = (const float*)d_in[4];
  float* out = (float*)d_out;

  float* state_c = (float*)d_ws;
  u16* state_h = (u16*)((char*)d_ws + 64 * 1024);
  u16* whk = (u16*)((char*)d_ws + 128 * 1024);
  u16* xg = (u16*)((char*)d_ws + (1 << 20));

  int chunkT = 1024;
  while (chunkT > 64 && (size_t)131072 * chunkT + (1 << 20) > ws_size)
    chunkT >>= 1;

  wh_pack<<<dim3(64), dim3(256), 0, stream>>>(Wfw, Wbw, whk);
  for (int t0 = 0; t0 < T_LEN; t0 += chunkT) {
    xg_gemm<<<dim3((32 * chunkT) / 64, 16, 2), dim3(256), 0, stream>>>(
        x, Wfw, bfw, Wbw, bbw, xg, t0, chunkT);
    rnn_chunk<<<dim3(4), dim3(512), 0, stream>>>(
        xg, Wfw, Wbw, whk, out, state_c, state_h, t0, t0 + chunkT, chunkT);
  }
}

// Round 16
// 5591.293 us; speedup vs baseline: 2.3153x; 2.2044x over previous
//
#include <hip/hip_runtime.h>

#define T_LEN 2048

typedef _Float16 f16x8 __attribute__((ext_vector_type(8)));
typedef float f32x4 __attribute__((ext_vector_type(4)));
typedef unsigned int u32;
typedef unsigned short u16;

__device__ __forceinline__ float sigm(float v) { return 1.f / (1.f + __expf(-v)); }

// swizzled addr into h tile A[16 seq][256] f16 (row stride 512B)
__device__ __forceinline__ void* swzA(_Float16* base, int row, int d) {
  int byte = row * 512 + d * 2;
  byte ^= (row & 7) << 4;
  return (void*)((char*)base + byte);
}

__device__ __forceinline__ void lstore(u32* p, u32 v) {
  asm volatile("global_store_dword %0, %1, off" ::"v"(p), "v"(v) : "memory");
}
__device__ __forceinline__ void issue3_sc0(const u32* p1, const u32* p2,
                                           const u32* p3, u32& a, u32& b, u32& c) {
  asm volatile(
      "global_load_dword %0, %3, off sc0\n\t"
      "global_load_dword %1, %4, off sc0\n\t"
      "global_load_dword %2, %5, off sc0"
      : "=&v"(a), "=&v"(b), "=&v"(c)
      : "v"(p1), "v"(p2), "v"(p3)
      : "memory");
}
__device__ __forceinline__ void wait_vm0(u32& a, u32& b, u32& c) {
  asm volatile("s_waitcnt vmcnt(0)" : "+v"(a), "+v"(b), "+v"(c)::"memory");
}

// ---------- Phase 1: xg = x @ Wx + bias (+1 forget), f16, layout [d*4+p] ----
// (verified R14/R15)
__global__ __launch_bounds__(256) void xg_gemm(
    const float* __restrict__ x, const float* __restrict__ Wfw,
    const float* __restrict__ bfw, const float* __restrict__ Wbw,
    const float* __restrict__ bbw, u16* __restrict__ xg, int t0, int chunkT) {
  const int dir = blockIdx.z;
  const int mrow0 = blockIdx.x * 64;
  const int ncol0 = blockIdx.y * 64;
  const float* W = dir ? Wbw : Wfw;
  const float* bias = dir ? bbw : bfw;
  const int tid = threadIdx.x;
  const int w = tid >> 6, lane = tid & 63, l15 = lane & 15, l4 = lane >> 4;

  __shared__ _Float16 At[64 * 32];
  __shared__ _Float16 Bt[64 * 32];

  const int b = mrow0 / chunkT;
  const int sbase = mrow0 % chunkT;

  f32x4 acc0 = {0,0,0,0}, acc1 = {0,0,0,0}, acc2 = {0,0,0,0}, acc3 = {0,0,0,0};
  const int ar = tid >> 2, acq = tid & 3;
  const int bc = tid >> 2, bkq = tid & 3;

  for (int kk0 = 0; kk0 < 256; kk0 += 32) {
    {
      const int sloc = sbase + ar;
      const int tx = dir ? (T_LEN - 1 - (t0 + sloc)) : (t0 + sloc);
      const float* xr = x + ((size_t)b * T_LEN + tx) * 256 + kk0 + 8 * acq;
      f32x4 v0 = *(const f32x4*)xr;
      f32x4 v1 = *(const f32x4*)(xr + 4);
      union { _Float16 h[8]; uint4 q; } u;
#pragma unroll
      for (int j = 0; j < 4; ++j) { u.h[j] = (_Float16)v0[j]; u.h[4 + j] = (_Float16)v1[j]; }
      int byte = ar * 64 + 16 * acq;  byte ^= (ar & 3) << 4;
      *(uint4*)((char*)At + byte) = u.q;
    }
    {
      const float* wc = W + (size_t)(kk0 + 8 * bkq) * 1024 + ncol0 + bc;
      union { _Float16 h[8]; uint4 q; } u;
#pragma unroll
      for (int j = 0; j < 8; ++j) u.h[j] = (_Float16)wc[(size_t)j * 1024];
      int byte = bc * 64 + 16 * bkq;  byte ^= (bc & 3) << 4;
      *(uint4*)((char*)Bt + byte) = u.q;
    }
    __syncthreads();
    f16x8 bfrag;
    {
      const int col = w * 16 + l15;
      int byte = col * 64 + 16 * l4;  byte ^= (col & 3) << 4;
      bfrag = *(const f16x8*)((char*)Bt + byte);
    }
#define XG_MT(mt, accv)                                                   \
    { const int row = mt * 16 + l15;                                      \
      int byte = row * 64 + 16 * l4;  byte ^= (row & 3) << 4;             \
      f16x8 afrag = *(const f16x8*)((char*)At + byte);                    \
      accv = __builtin_amdgcn_mfma_f32_16x16x32_f16(afrag, bfrag, accv, 0, 0, 0); }
    XG_MT(0, acc0) XG_MT(1, acc1) XG_MT(2, acc2) XG_MT(3, acc3)
#undef XG_MT
    __syncthreads();
  }
  const int gcol = ncol0 + w * 16 + l15;
  const int pp = gcol >> 8, dd = gcol & 255;
  const float badd = bias[gcol] + ((pp == 2) ? 1.f : 0.f);
#define XG_ST(mt, accv)                                                   \
  _Pragma("unroll") for (int v = 0; v < 4; ++v) {                         \
    const int sloc = sbase + mt * 16 + 4 * l4 + v;                        \
    union { _Float16 hf; u16 us; } cv;                                    \
    cv.hf = (_Float16)(accv[v] + badd);                                   \
    xg[((size_t)(dir * 32 + b) * chunkT + sloc) * 1024 + dd * 4 + pp] = cv.us; }
  XG_ST(0, acc0) XG_ST(1, acc1) XG_ST(2, acc2) XG_ST(3, acc3)
#undef XG_ST
}

// ---------- Phase 2: recurrence (R9 skeleton, K=256 h-only). ----------
// 32 WGs x 1024 thr; active iff (bid&7)<4. group g=bid&7 {dir,bh}: 16 seqs;
// member m=bid>>3 owns dims [64m..64m+63]; members at bids {g,g+8,g+16,g+24}
// == g (mod 8) -> same XCD under round-robin dispatch (speed-only bet).
// Wave w: part p=w>>2, 16 cols at p*256+64m+(w&3)*16; Wh K=256 = 8 frags (regs).
// Exchange line u32 {stamp16|h-f16}: DUAL publish (plain store -> local L2;
// agent store -> MALL). Poll local sc0 (fast same-XCD), permanent fallback to
// MALL after 4096 fails (first step, tolerates dispatch skew) / 64 (steady).
__global__ __launch_bounds__(1024, 4) void rnn_step(
    const u16* __restrict__ xg, const float* __restrict__ Wfw,
    const float* __restrict__ Wbw, float* __restrict__ out,
    float* __restrict__ state_c, u16* __restrict__ state_h,
    u32* __restrict__ gmbox, u32* __restrict__ lmbox, u32* __restrict__ flags,
    int t0, int t1, int chunkT) {
  const int bid = blockIdx.x;
  if ((bid & 7) >= 4) return;
  const int g = bid & 7;
  const int m = bid >> 3;
  const int dir = g >> 1, bh = g & 1;
  const int tid = threadIdx.x;
  const int w = tid >> 6, lane = tid & 63, l15 = lane & 15, l4 = lane >> 4;
  const float* W = dir ? Wbw : Wfw;

  __shared__ _Float16 A[16 * 256];  // 8KB h(t-1), swizzled
  __shared__ float G[16 * 260];     // gate transpose

  // weights: K rows 256..511 (h part), 8 frags = 32 VGPR
  const int p = w >> 2;
  const int gcol = p * 256 + 64 * m + (w & 3) * 16 + l15;
  f16x8 wB[8];
#pragma unroll
  for (int kt = 0; kt < 8; ++kt) {
    const int kb = 256 + kt * 32 + l4 * 8;
    f16x8 h;
#pragma unroll
    for (int j = 0; j < 8; ++j) h[j] = (_Float16)W[(size_t)(kb + j) * 1024 + gcol];
    wB[kt] = h;
  }

  const int cs = tid >> 6, cd = tid & 63;
  const int dim = 64 * m + cd;
  const int sidx = (dir * 32 + bh * 16 + cs) * 256 + dim;
  const int pd1 = 64 * ((m + 1) & 3) + cd;
  const int pd2 = 64 * ((m + 2) & 3) + cd;
  const int pd3 = 64 * ((m + 3) & 3) + cd;
  u32* Gm = gmbox + g * (2 * 16 * 256);
  u32* Lm = lmbox + g * (2 * 16 * 256);

  float c;
  if (t0 == 0) {
    c = 0.f;
    // zero the local lines THIS thread polls (both bufs) -> our L2
#pragma unroll
    for (int b = 0; b < 2; ++b) {
      u32* Lb = Lm + (b * 16 + cs) * 256;
      lstore(Lb + pd1, 0u);
      lstore(Lb + pd2, 0u);
      lstore(Lb + pd3, 0u);
    }
    // stage h(-1)=0 (own + 3 peer slots covers all 256 dims)
    *(u16*)swzA(A, cs, dim) = 0;
    *(u16*)swzA(A, cs, pd1) = 0;
    *(u16*)swzA(A, cs, pd2) = 0;
    *(u16*)swzA(A, cs, pd3) = 0;
    __syncthreads();  // compiler drains vmcnt before barrier
    if (tid == 0) {   // handshake: no publish until all members zeroed
      __hip_atomic_store(flags + g * 4 + m, 1, __ATOMIC_RELEASE,
                         __HIP_MEMORY_SCOPE_AGENT);
      int got;
      do {
        got = 0;
        for (int q = 0; q < 4; ++q)
          got += __hip_atomic_load(flags + g * 4 + q, __ATOMIC_ACQUIRE,
                                   __HIP_MEMORY_SCOPE_AGENT);
      } while (got < 4);
    }
    __syncthreads();
  } else {
    c = state_c[sidx];
    const u16* sh = state_h + (dir * 32 + bh * 16 + cs) * 256;
    *(u16*)swzA(A, cs, dim) = sh[dim];
    *(u16*)swzA(A, cs, pd1) = sh[pd1];
    *(u16*)swzA(A, cs, pd2) = sh[pd2];
    *(u16*)swzA(A, cs, pd3) = sh[pd3];
  }

  const u16* xgp = xg + ((size_t)(dir * 32 + bh * 16 + cs) * chunkT) * 1024 + dim * 4;
  const int tx0 = dir ? (T_LEN - 1 - t0) : t0;
  float* outp = out + ((size_t)(bh * 16 + cs) * T_LEN + tx0) * 512 + dir * 256 + dim;
  const long ostep = dir ? -512 : 512;

  bool use_global = false;
  u32 s1 = 0, s2 = 0, s3 = 0;
  u16 hlast = 0;

  for (int s = t0; s < t1; ++s) {
    if (s > t0) {
      const u32 want = (u32)s;
      const int rb = (s - 1) & 1;
      u32* Lp = Lm + (rb * 16 + cs) * 256;
      u32* Gp = Gm + (rb * 16 + cs) * 256;
      if (!use_global) {
        wait_vm0(s1, s2, s3);  // consume pre-issued samples
        int tries = 0;
        const int maxtries = (s == t0 + 1) ? 4096 : 64;
        while ((s1 >> 16) != want || (s2 >> 16) != want || (s3 >> 16) != want) {
          if (++tries > maxtries) { use_global = true; break; }
          issue3_sc0(Lp + pd1, Lp + pd2, Lp + pd3, s1, s2, s3);
          wait_vm0(s1, s2, s3);
        }
      }
      if (use_global) {
        for (;;) {
          s1 = __hip_atomic_load(Gp + pd1, __ATOMIC_RELAXED, __HIP_MEMORY_SCOPE_AGENT);
          s2 = __hip_atomic_load(Gp + pd2, __ATOMIC_RELAXED, __HIP_MEMORY_SCOPE_AGENT);
          s3 = __hip_atomic_load(Gp + pd3, __ATOMIC_RELAXED, __HIP_MEMORY_SCOPE_AGENT);
          if ((s1 >> 16) == want && (s2 >> 16) == want && (s3 >> 16) == want) break;
        }
      }
      *(u16*)swzA(A, cs, pd1) = (u16)(s1 & 0xffffu);
      *(u16*)swzA(A, cs, pd2) = (u16)(s2 & 0xffffu);
      *(u16*)swzA(A, cs, pd3) = (u16)(s3 & 0xffffu);
    }
    __syncthreads();  // B2: A complete (own staged at cell of s-1, peers above)

    // xg gates for this step (ushort4: i,j,f,o), used at cell
    const ushort4 xv = *(const ushort4*)xgp;
    xgp += 1024;

    // MFMA K=256 over h(t-1)
    f32x4 acc = {0.f, 0.f, 0.f, 0.f};
#pragma unroll
    for (int kt = 0; kt < 8; ++kt) {
      int byte = l15 * 512 + kt * 64 + l4 * 16;
      byte ^= (l15 & 7) << 4;
      f16x8 a = *(const f16x8*)((const char*)A + byte);
      acc = __builtin_amdgcn_mfma_f32_16x16x32_f16(a, wB[kt], acc, 0, 0, 0);
    }
    {  // transpose to G (C/D: col=l15, row=4*l4+v)
      const int Gcol = p * 64 + (w & 3) * 16 + l15;
      float* gw = G + Gcol;
      const int r = l4 * 4;
#pragma unroll
      for (int v = 0; v < 4; ++v) gw[(r + v) * 260] = acc[v];
    }
    __syncthreads();  // B3: gates ready; A reads of step s done

    // cell
    const float* Gp2 = G + cs * 260 + cd;
    const float gi = Gp2[0]   + (float)*(const _Float16*)&xv.x;
    const float gj = Gp2[64]  + (float)*(const _Float16*)&xv.y;
    const float gf = Gp2[128] + (float)*(const _Float16*)&xv.z;
    const float go = Gp2[192] + (float)*(const _Float16*)&xv.w;
    c = c * sigm(gf) + sigm(gi) * (2.f * sigm(gj + gj) - 1.f);
    const float h = (2.f * sigm(c + c) - 1.f) * sigm(go);

    union { _Float16 hf; u16 us; } cv;
    cv.hf = (_Float16)h;
    hlast = cv.us;
    const u32 pay = (((u32)(s + 1)) << 16) | (u32)cv.us;
    const int wb = s & 1;
    lstore(Lm + (wb * 16 + cs) * 256 + dim, pay);                 // L2 fast path
    __hip_atomic_store(Gm + (wb * 16 + cs) * 256 + dim, pay,      // MALL fallback
                       __ATOMIC_RELAXED, __HIP_MEMORY_SCOPE_AGENT);
    *(u16*)swzA(A, cs, dim) = cv.us;  // own-h stage (reads done at B3)
    __builtin_nontemporal_store(h, outp);
    outp += ostep;

    // pre-issue next samples (local path only; overlaps peers' latency)
    if (!use_global && s + 1 < t1) {
      u32* Ln = Lm + ((s & 1) * 16 + cs) * 256;
      issue3_sc0(Ln + pd1, Ln + pd2, Ln + pd3, s1, s2, s3);
    }
  }

  state_c[sidx] = c;
  state_h[sidx] = hlast;
}

extern "C" void kernel_launch(void* const* d_in, const int* in_sizes, int n_in,
                              void* d_out, int out_size, void* d_ws,
                              size_t ws_size, hipStream_t stream) {
  const float* x = (const float*)d_in[0];
  const float* Wfw = (const float*)d_in[1];
  const float* bfw = (const float*)d_in[2];
  const float* Wbw = (const float*)d_in[3];
  const float* bbw = (const float*)d_in[4];
  float* out = (float*)d_out;

  // ws: [0,128K) gmbox | [128K,+64B) flags | [132K,260K) lmbox |
  //     [260K,324K) state_c | [324K,340K) state_h | [1M,..) xg
  u32* gmbox = (u32*)d_ws;
  u32* flags = (u32*)((char*)d_ws + 128 * 1024);
  u32* lmbox = (u32*)((char*)d_ws + 132 * 1024);
  float* state_c = (float*)((char*)d_ws + 260 * 1024);
  u16* state_h = (u16*)((char*)d_ws + 324 * 1024);
  u16* xg = (u16*)((char*)d_ws + (1 << 20));

  int chunkT = 1024;
  while (chunkT > 64 && (size_t)131072 * chunkT + (1 << 20) > ws_size)
    chunkT >>= 1;

  (void)hipMemsetAsync(d_ws, 0, 132 * 1024, stream);  // gmbox + flags

  for (int t0 = 0; t0 < T_LEN; t0 += chunkT) {
    xg_gemm<<<dim3((32 * chunkT) / 64, 16, 2), dim3(256), 0, stream>>>(
        x, Wfw, bfw, Wbw, bbw, xg, t0, chunkT);
    rnn_step<<<dim3(32), dim3(1024), 0, stream>>>(
        xg, Wfw, Wbw, out, state_c, state_h, gmbox, lmbox, flags,
        t0, t0 + chunkT, chunkT);
  }
}